// Round 1
// baseline (538.480 us; speedup 1.0000x reference)
//
#include <hip/hip_runtime.h>

typedef unsigned short ushort_t;

typedef __bf16 bf16x8 __attribute__((ext_vector_type(8)));
typedef float f32x16 __attribute__((ext_vector_type(16)));
typedef float f32x4 __attribute__((ext_vector_type(4)));

#define N_TOK 8192

// workspace byte offsets
#define OFF_X1B 0u
#define OFF_X2B 16777216u
#define OFF_WQB 33554432u
#define OFF_WKB 34603008u
#define OFF_WVB 35651584u
#define OFF_Q   36700160u
#define OFF_K   45088768u
#define OFF_VT  53477376u
#define OFF_CS  61865984u
#define OFF_L   61868032u
#define OFF_O   61999104u

__device__ __forceinline__ float bf2f(ushort_t u) {
    unsigned x = ((unsigned)u) << 16;
    return __uint_as_float(x);
}
__device__ __forceinline__ ushort_t f2bf(float f) {
    unsigned u = __float_as_uint(f);
    return (ushort_t)((u + 0x7FFFu + ((u >> 16) & 1u)) >> 16);
}

typedef __attribute__((address_space(1))) void gv_t;
typedef __attribute__((address_space(3))) void lv_t;
__device__ __forceinline__ void gl16p(const void* g, void* l) {
    __builtin_amdgcn_global_load_lds((gv_t*)g, (lv_t*)l, 16, 0, 0);
}

__device__ __forceinline__ f32x16 z16() {
    f32x16 v;
#pragma unroll
    for (int i = 0; i < 16; ++i) v[i] = 0.f;
    return v;
}
__device__ __forceinline__ f32x4 z4() {
    f32x4 v;
#pragma unroll
    for (int i = 0; i < 4; ++i) v[i] = 0.f;
    return v;
}

// ---------------- convert f32 -> bf16 (x1, x2, Wq, Wk, Wv) ----------------
__global__ __launch_bounds__(256) void cvt_kernel(
    const float* __restrict__ x1, const float* __restrict__ x2,
    const float* __restrict__ Wq, const float* __restrict__ Wk,
    const float* __restrict__ Wv, char* __restrict__ ws)
{
    ushort_t* x1b = (ushort_t*)(ws + OFF_X1B);
    ushort_t* x2b = (ushort_t*)(ws + OFF_X2B);
    ushort_t* wqb = (ushort_t*)(ws + OFF_WQB);
    ushort_t* wkb = (ushort_t*)(ws + OFF_WKB);
    ushort_t* wvb = (ushort_t*)(ws + OFF_WVB);
    const unsigned TOT4 = 4587520u;
    for (unsigned idx = blockIdx.x * 256u + threadIdx.x; idx < TOT4; idx += gridDim.x * 256u) {
        unsigned i = idx;
        const float* s; ushort_t* d;
        if (i < 2097152u)      { s = x1; d = x1b; }
        else if (i < 4194304u) { i -= 2097152u; s = x2; d = x2b; }
        else if (i < 4325376u) { i -= 4194304u; s = Wq; d = wqb; }
        else if (i < 4456448u) { i -= 4325376u; s = Wk; d = wkb; }
        else                   { i -= 4456448u; s = Wv; d = wvb; }
        float4 v = *(const float4*)(s + (size_t)i * 4);
        ushort4 o;
        o.x = f2bf(v.x); o.y = f2bf(v.y); o.z = f2bf(v.z); o.w = f2bf(v.w);
        *(ushort4*)(d + (size_t)i * 4) = o;
    }
}

// ---------------- projection GEMMs (m97-style 128x128 tile, BK=64) ----------------
// z=0: q = x1 @ Wq^T + bq   [8192][512]
// z=1: k = x2 @ Wk^T + bk   [8192][512]
// z=2: vT = (x2 @ Wv^T + bv)^T = Wv @ x2^T (+bv per row)  [512][8192]
__global__ __launch_bounds__(256) void proj_kernel(
    const char* __restrict__ ws,
    const float* __restrict__ bq, const float* __restrict__ bk, const float* __restrict__ bv)
{
    __shared__ ushort_t Al[128 * 64];
    __shared__ ushort_t Bl[128 * 64];
    const int z = blockIdx.y;
    const ushort_t* A; const ushort_t* B; const float* bias; ushort_t* C;
    int ldc; bool brow;
    if (z == 0)      { A = (const ushort_t*)(ws + OFF_X1B); B = (const ushort_t*)(ws + OFF_WQB); bias = bq; C = (ushort_t*)(ws + OFF_Q);  ldc = 512;  brow = false; }
    else if (z == 1) { A = (const ushort_t*)(ws + OFF_X2B); B = (const ushort_t*)(ws + OFF_WKB); bias = bk; C = (ushort_t*)(ws + OFF_K);  ldc = 512;  brow = false; }
    else             { A = (const ushort_t*)(ws + OFF_WVB); B = (const ushort_t*)(ws + OFF_X2B); bias = bv; C = (ushort_t*)(ws + OFF_VT); ldc = 8192; brow = true;  }
    const int b = blockIdx.x;
    int tm, tn;
    if (z < 2) { tm = b >> 2; tn = b & 3; } else { tm = b & 3; tn = b >> 2; }
    const int tid = threadIdx.x;
    const unsigned lane = tid & 63, wid = tid >> 6;
    const unsigned wm = wid >> 1, wn = wid & 1;

    f32x4 acc[4][4];
#pragma unroll
    for (int i = 0; i < 4; ++i)
#pragma unroll
        for (int j = 0; j < 4; ++j) acc[i][j] = z4();

    const char* Abase = (const char*)A + (size_t)(tm * 128) * 2048;
    const char* Bbase = (const char*)B + (size_t)(tn * 128) * 2048;

    for (int ks = 0; ks < 16; ++ks) {
#pragma unroll
        for (int c = 0; c < 4; ++c) {
            unsigned g = wid * 256u + c * 64u + lane;
            unsigned r = g >> 3, sl = g & 7;
            gl16p(Abase + (size_t)r * 2048 + ks * 128 + sl * 16, (char*)Al + g * 16);
            gl16p(Bbase + (size_t)r * 2048 + ks * 128 + sl * 16, (char*)Bl + g * 16);
        }
        __syncthreads();
#pragma unroll
        for (int kk = 0; kk < 2; ++kk) {
            bf16x8 af[4], bg[4];
#pragma unroll
            for (int mt = 0; mt < 4; ++mt) {
                unsigned row = wm * 64 + mt * 16 + (lane & 15);
                af[mt] = *(const bf16x8*)((const char*)Al + row * 128 + kk * 64 + (lane >> 4) * 16);
            }
#pragma unroll
            for (int nt = 0; nt < 4; ++nt) {
                unsigned row = wn * 64 + nt * 16 + (lane & 15);
                bg[nt] = *(const bf16x8*)((const char*)Bl + row * 128 + kk * 64 + (lane >> 4) * 16);
            }
#pragma unroll
            for (int mt = 0; mt < 4; ++mt)
#pragma unroll
                for (int nt = 0; nt < 4; ++nt)
                    acc[mt][nt] = __builtin_amdgcn_mfma_f32_16x16x32_bf16(af[mt], bg[nt], acc[mt][nt], 0, 0, 0);
        }
        __syncthreads();
    }
#pragma unroll
    for (int mt = 0; mt < 4; ++mt)
#pragma unroll
        for (int nt = 0; nt < 4; ++nt)
#pragma unroll
            for (int rg = 0; rg < 4; ++rg) {
                int grow = tm * 128 + wm * 64 + mt * 16 + (lane >> 4) * 4 + rg;
                int gcol = tn * 128 + wn * 64 + nt * 16 + (lane & 15);
                float v = acc[mt][nt][rg] + (brow ? bias[grow] : bias[gcol]);
                C[(size_t)grow * ldc + gcol] = f2bf(v);
            }
}

// ---------------- colsum of v (row sums of vT) ----------------
__global__ __launch_bounds__(256) void colsum_kernel(const char* __restrict__ ws)
{
    const ushort_t* vT = (const ushort_t*)(ws + OFF_VT);
    float* cs = (float*)(ws + OFF_CS);
    const int d = blockIdx.x;
    const ushort4* row = (const ushort4*)(vT + (size_t)d * 8192);
    float s = 0.f;
    for (int i = threadIdx.x; i < 2048; i += 256) {
        ushort4 u = row[i];
        s += bf2f(u.x) + bf2f(u.y) + bf2f(u.z) + bf2f(u.w);
    }
    __shared__ float red[256];
    red[threadIdx.x] = s;
    __syncthreads();
    for (int st = 128; st > 0; st >>= 1) {
        if ((int)threadIdx.x < st) red[threadIdx.x] += red[threadIdx.x + st];
        __syncthreads();
    }
    if (threadIdx.x == 0) cs[d] = red[0];
}

// ---------------- fused attention (flash-style, no max tracking) ----------------
// block: 128 q-rows (qb), k-split g. 8 waves (2m x 4n). BN=128 k-tile.
// LDS: Qc dbuf 2x16KB | Kc dbuf 2x16KB | Vc dbuf 2x16KB | P 32KB = 128KB
#define QOFF 0u
#define KOFF 32768u
#define VOFF 65536u
#define POFF 98304u

__global__ __launch_bounds__(512, 2) void attn_kernel(const char* __restrict__ ws, int G, int NT)
{
    extern __shared__ char smem[];
    const ushort_t* qws = (const ushort_t*)(ws + OFF_Q);
    const ushort_t* kws = (const ushort_t*)(ws + OFF_K);
    const ushort_t* vT  = (const ushort_t*)(ws + OFF_VT);
    float* Opart = (float*)(ws + OFF_O);
    float* lpart = (float*)(ws + OFF_L);

    const int qb = blockIdx.x, g = blockIdx.y;
    const int tid = threadIdx.x;
    const unsigned lane = tid & 63, wid = tid >> 6;
    const unsigned wm = wid >> 2, wn = wid & 3;
    const int L = NT * 128;
    const int j0 = g * L;
    const int qrow0 = qb * 128;

    bf16x8 vone;
#pragma unroll
    for (int i = 0; i < 8; ++i) vone[i] = (__bf16)1.0f;

    f32x16 oacc[2][4];
#pragma unroll
    for (int i = 0; i < 2; ++i)
#pragma unroll
        for (int j = 0; j < 4; ++j) oacc[i][j] = z16();
    f32x16 lacc = z16();

    const char* qsb = (const char*)qws + (size_t)qrow0 * 1024;

    // prologue: stage QK (kt=0, dc=0) into buf0
    {
        const char* ksb0 = (const char*)kws + (size_t)j0 * 1024;
#pragma unroll
        for (int c = 0; c < 2; ++c) {
            unsigned gg = wid * 128u + c * 64u + lane;
            unsigned r = gg >> 3, sl = (gg & 7) ^ (r & 7);
            gl16p(qsb + (size_t)r * 1024 + sl * 16, smem + QOFF + gg * 16);
            gl16p(ksb0 + (size_t)r * 1024 + sl * 16, smem + KOFF + gg * 16);
        }
    }

    for (int kt = 0; kt < NT; ++kt) {
        const int jt = j0 + kt * 128;
        const char* ksb = (const char*)kws + (size_t)jt * 1024;
        __syncthreads();   // QK(kt,0) ready

        f32x16 s0 = z16(), s1 = z16();
#pragma unroll
        for (int dc = 0; dc < 8; ++dc) {
            if (dc < 7) {
                unsigned qoff = QOFF + ((dc + 1) & 1) * 16384u;
                unsigned koff = KOFF + ((dc + 1) & 1) * 16384u;
#pragma unroll
                for (int c = 0; c < 2; ++c) {
                    unsigned gg = wid * 128u + c * 64u + lane;
                    unsigned r = gg >> 3, sl = (gg & 7) ^ (r & 7);
                    gl16p(qsb + (size_t)r * 1024 + (dc + 1) * 128 + sl * 16, smem + qoff + gg * 16);
                    gl16p(ksb + (size_t)r * 1024 + (dc + 1) * 128 + sl * 16, smem + koff + gg * 16);
                }
            } else {
                // prefetch V chunk 0 into buf0
                const char* vsb = (const char*)vT + (size_t)jt * 2;
#pragma unroll
                for (int c = 0; c < 2; ++c) {
                    unsigned gg = wid * 128u + c * 64u + lane;
                    unsigned d = gg >> 1, sl = (gg & 1) ^ ((d >> 2) & 1);
                    gl16p(vsb + (size_t)d * 16384 + sl * 16, smem + VOFF + gg * 16);
                }
            }
            {
                const char* qlb = smem + QOFF + (dc & 1) * 16384u;
                const char* klb = smem + KOFF + (dc & 1) * 16384u;
                unsigned r0 = wm * 64 + (lane & 31);
                unsigned rj = wn * 32 + (lane & 31);
#pragma unroll
                for (int kk = 0; kk < 4; ++kk) {
                    unsigned kg = (kk << 1) + (lane >> 5);
                    bf16x8 bk = *(const bf16x8*)(klb + rj * 128 + ((kg ^ (rj & 7)) << 4));
                    bf16x8 a0 = *(const bf16x8*)(qlb + r0 * 128 + ((kg ^ (r0 & 7)) << 4));
                    bf16x8 a1 = *(const bf16x8*)(qlb + (r0 + 32) * 128 + ((kg ^ (r0 & 7)) << 4));
                    s0 = __builtin_amdgcn_mfma_f32_32x32x16_bf16(a0, bk, s0, 0, 0, 0);
                    s1 = __builtin_amdgcn_mfma_f32_32x32x16_bf16(a1, bk, s1, 0, 0, 0);
                }
            }
            __syncthreads();
        }

        // epilogue: p = exp(tanh(s)/sqrt(512)) -> bf16 -> P_lds (swizzled)
        {
            const float csc = 0.044194173824159216f;  // 1/sqrt(512)
            unsigned colb = wn * 32 + (lane & 31);
#pragma unroll
            for (int sm = 0; sm < 2; ++sm) {
#pragma unroll
                for (int rg = 0; rg < 16; ++rg) {
                    float s = sm ? s1[rg] : s0[rg];
                    float e = __expf(2.0f * s);
                    float rr = __builtin_amdgcn_rcpf(1.0f + e);
                    float t = fmaf(-2.0f, rr, 1.0f);      // tanh(s)
                    float u = t * csc;
                    float p = fmaf(u, fmaf(u, 0.5f, 1.0f), 1.0f);  // exp(u), |u|<=0.045
                    unsigned row = wm * 64 + sm * 32 + (rg & 3) + ((rg >> 2) << 3) + ((lane >> 5) << 2);
                    unsigned byteoff = POFF + row * 256 + ((((colb >> 3) ^ (row & 15)) << 4) | ((colb & 7) << 1));
                    *(ushort_t*)(smem + byteoff) = f2bf(p);
                }
            }
        }
        if (kt + 1 < NT) {
            // stage QK (kt+1, dc=0) into buf0
            const char* ksb2 = (const char*)kws + (size_t)(jt + 128) * 1024;
#pragma unroll
            for (int c = 0; c < 2; ++c) {
                unsigned gg = wid * 128u + c * 64u + lane;
                unsigned r = gg >> 3, sl = (gg & 7) ^ (r & 7);
                gl16p(qsb + (size_t)r * 1024 + sl * 16, smem + QOFF + gg * 16);
                gl16p(ksb2 + (size_t)r * 1024 + sl * 16, smem + KOFF + gg * 16);
            }
        }
        __syncthreads();  // P complete + Vc0 ready

        // PV phase: 8 chunks of 16 j-rows
#pragma unroll
        for (int vc = 0; vc < 8; ++vc) {
            if (vc < 7) {
                const char* vsb = (const char*)vT + (size_t)(jt + (vc + 1) * 16) * 2;
                unsigned voff = VOFF + ((vc + 1) & 1) * 16384u;
#pragma unroll
                for (int c = 0; c < 2; ++c) {
                    unsigned gg = wid * 128u + c * 64u + lane;
                    unsigned d = gg >> 1, sl = (gg & 1) ^ ((d >> 2) & 1);
                    gl16p(vsb + (size_t)d * 16384 + sl * 16, smem + voff + gg * 16);
                }
            }
            {
                const char* vlb = smem + VOFF + (vc & 1) * 16384u;
                unsigned r0 = wm * 64 + (lane & 31);
                unsigned jg = (vc << 1) + (lane >> 5);
                bf16x8 aP0 = *(const bf16x8*)(smem + POFF + r0 * 256 + ((jg ^ (r0 & 15)) << 4));
                bf16x8 aP1 = *(const bf16x8*)(smem + POFF + (r0 + 32) * 256 + ((jg ^ (r0 & 15)) << 4));
#pragma unroll
                for (int nt = 0; nt < 4; ++nt) {
                    unsigned d = wn * 128 + nt * 32 + (lane & 31);
                    bf16x8 bV = *(const bf16x8*)(vlb + d * 32 + (((lane >> 5) ^ ((d >> 2) & 1)) << 4));
                    oacc[0][nt] = __builtin_amdgcn_mfma_f32_32x32x16_bf16(aP0, bV, oacc[0][nt], 0, 0, 0);
                    oacc[1][nt] = __builtin_amdgcn_mfma_f32_32x32x16_bf16(aP1, bV, oacc[1][nt], 0, 0, 0);
                }
                if (wn < 2)
                    lacc = __builtin_amdgcn_mfma_f32_32x32x16_bf16(wn ? aP1 : aP0, vone, lacc, 0, 0, 0);
            }
            __syncthreads();
        }
    }

    // writeout partials
#pragma unroll
    for (int pm = 0; pm < 2; ++pm)
#pragma unroll
        for (int nt = 0; nt < 4; ++nt)
#pragma unroll
            for (int rg = 0; rg < 16; ++rg) {
                unsigned row = qrow0 + wm * 64 + pm * 32 + (rg & 3) + ((rg >> 2) << 3) + ((lane >> 5) << 2);
                unsigned col = wn * 128 + nt * 32 + (lane & 31);
                Opart[((size_t)g * N_TOK + row) * 512 + col] = oacc[pm][nt][rg];
            }
    if (wn < 2 && (lane & 31) == 0) {
#pragma unroll
        for (int rg = 0; rg < 16; ++rg) {
            unsigned row = qrow0 + wm * 64 + wn * 32 + (rg & 3) + ((rg >> 2) << 3) + ((lane >> 5) << 2);
            lpart[g * N_TOK + row] = lacc[rg];
        }
    }
}

// ---------------- final combine ----------------
__global__ __launch_bounds__(256) void out_kernel(const char* __restrict__ ws, float* __restrict__ out, int G)
{
    const float* Opart = (const float*)(ws + OFF_O);
    const float* lpart = (const float*)(ws + OFF_L);
    const float* cs    = (const float*)(ws + OFF_CS);
    unsigned idx = blockIdx.x * 256u + threadIdx.x;   // [0, 1048576)
    unsigned i = idx >> 7, dq = idx & 127;
    float ls = 0.f;
    for (int g = 0; g < G; ++g) ls += lpart[g * N_TOK + i];
    float4 ov; ov.x = 0.f; ov.y = 0.f; ov.z = 0.f; ov.w = 0.f;
    for (int g = 0; g < G; ++g) {
        const float4* p = (const float4*)(Opart + ((size_t)g * N_TOK + i) * 512);
        float4 t = p[dq];
        ov.x += t.x; ov.y += t.y; ov.z += t.z; ov.w += t.w;
    }
    float4 c = ((const float4*)cs)[dq];
    float rinv = 1.0f / ls;
    const float inv = 1.0f / 8191.0f;
    float4 r;
    r.x = (c.x - ov.x * rinv) * inv;
    r.y = (c.y - ov.y * rinv) * inv;
    r.z = (c.z - ov.z * rinv) * inv;
    r.w = (c.w - ov.w * rinv) * inv;
    ((float4*)out)[idx] = r;
}

extern "C" void kernel_launch(void* const* d_in, const int* in_sizes, int n_in,
                              void* d_out, int out_size, void* d_ws, size_t ws_size,
                              hipStream_t stream)
{
    const float* x1 = (const float*)d_in[0];
    const float* x2 = (const float*)d_in[1];
    const float* Wq = (const float*)d_in[2];
    const float* bq = (const float*)d_in[3];
    const float* Wk = (const float*)d_in[4];
    const float* bk = (const float*)d_in[5];
    const float* Wv = (const float*)d_in[6];
    const float* bv = (const float*)d_in[7];
    char* ws = (char*)d_ws;
    float* out = (float*)d_out;

    int G = 4;
    while (G > 1 && ws_size < (size_t)OFF_O + (size_t)G * 16777216u) G >>= 1;
    int NT = 64 / G;

    (void)hipFuncSetAttribute((const void*)attn_kernel,
                              hipFuncAttributeMaxDynamicSharedMemorySize, 131072);

    cvt_kernel<<<4096, 256, 0, stream>>>(x1, x2, Wq, Wk, Wv, ws);
    proj_kernel<<<dim3(256, 3), 256, 0, stream>>>(ws, bq, bk, bv);
    colsum_kernel<<<512, 256, 0, stream>>>(ws);
    attn_kernel<<<dim3(64, G), 512, 131072, stream>>>(ws, G, NT);
    out_kernel<<<4096, 256, 0, stream>>>(ws, out, G);
}

// Round 2
// 277.371 us; speedup vs baseline: 1.9414x; 1.9414x over previous
//
#include <hip/hip_runtime.h>

typedef unsigned short ushort_t;

typedef __bf16 bf16x8 __attribute__((ext_vector_type(8)));
typedef float f32x4 __attribute__((ext_vector_type(4)));

// workspace byte offsets
#define OFF_X1B 0u
#define OFF_X2B 16777216u
#define OFF_WQB 33554432u
#define OFF_WKB 34603008u
#define OFF_WVB 35651584u
#define OFF_Q   36700160u
#define OFF_K   45088768u
#define OFF_VT  53477376u
#define OFF_CS  61865984u
#define OFF_L   61868032u
#define OFF_L2  61900800u
#define OFF_O   61933568u
#define OFF_O2  78710784u
#define OFF_P   95488000u

__device__ __forceinline__ float bf2f(ushort_t u) {
    unsigned x = ((unsigned)u) << 16;
    return __uint_as_float(x);
}
__device__ __forceinline__ ushort_t f2bf(float f) {
    unsigned u = __float_as_uint(f);
    return (ushort_t)((u + 0x7FFFu + ((u >> 16) & 1u)) >> 16);
}

typedef __attribute__((address_space(1))) void gv_t;
typedef __attribute__((address_space(3))) void lv_t;
__device__ __forceinline__ void gl16p(const void* g, void* l) {
    __builtin_amdgcn_global_load_lds((gv_t*)g, (lv_t*)l, 16, 0, 0);
}

__device__ __forceinline__ f32x4 z4() {
    f32x4 v;
#pragma unroll
    for (int i = 0; i < 4; ++i) v[i] = 0.f;
    return v;
}

// ---------------- convert f32 -> bf16 (x1, x2, Wq, Wk, Wv) ----------------
__global__ __launch_bounds__(256) void cvt_kernel(
    const float* __restrict__ x1, const float* __restrict__ x2,
    const float* __restrict__ Wq, const float* __restrict__ Wk,
    const float* __restrict__ Wv, char* __restrict__ ws)
{
    ushort_t* x1b = (ushort_t*)(ws + OFF_X1B);
    ushort_t* x2b = (ushort_t*)(ws + OFF_X2B);
    ushort_t* wqb = (ushort_t*)(ws + OFF_WQB);
    ushort_t* wkb = (ushort_t*)(ws + OFF_WKB);
    ushort_t* wvb = (ushort_t*)(ws + OFF_WVB);
    const unsigned TOT4 = 4587520u;
    for (unsigned idx = blockIdx.x * 256u + threadIdx.x; idx < TOT4; idx += gridDim.x * 256u) {
        unsigned i = idx;
        const float* s; ushort_t* d;
        if (i < 2097152u)      { s = x1; d = x1b; }
        else if (i < 4194304u) { i -= 2097152u; s = x2; d = x2b; }
        else if (i < 4325376u) { i -= 4194304u; s = Wq; d = wqb; }
        else if (i < 4456448u) { i -= 4325376u; s = Wk; d = wkb; }
        else                   { i -= 4456448u; s = Wv; d = wvb; }
        float4 v = *(const float4*)(s + (size_t)i * 4);
        ushort4 o;
        o.x = f2bf(v.x); o.y = f2bf(v.y); o.z = f2bf(v.z); o.w = f2bf(v.w);
        *(ushort4*)(d + (size_t)i * 4) = o;
    }
}

// ---------------- projection GEMMs (m97-style 128x128 tile, BK=64) ----------------
__global__ __launch_bounds__(256) void proj_kernel(
    const char* __restrict__ ws,
    const float* __restrict__ bq, const float* __restrict__ bk, const float* __restrict__ bv)
{
    __shared__ ushort_t Al[128 * 64];
    __shared__ ushort_t Bl[128 * 64];
    const int z = blockIdx.y;
    const ushort_t* A; const ushort_t* B; const float* bias; ushort_t* C;
    int ldc; bool brow;
    if (z == 0)      { A = (const ushort_t*)(ws + OFF_X1B); B = (const ushort_t*)(ws + OFF_WQB); bias = bq; C = (ushort_t*)(ws + OFF_Q);  ldc = 512;  brow = false; }
    else if (z == 1) { A = (const ushort_t*)(ws + OFF_X2B); B = (const ushort_t*)(ws + OFF_WKB); bias = bk; C = (ushort_t*)(ws + OFF_K);  ldc = 512;  brow = false; }
    else             { A = (const ushort_t*)(ws + OFF_WVB); B = (const ushort_t*)(ws + OFF_X2B); bias = bv; C = (ushort_t*)(ws + OFF_VT); ldc = 8192; brow = true;  }
    const int b = blockIdx.x;
    int tm, tn;
    if (z < 2) { tm = b >> 2; tn = b & 3; } else { tm = b & 3; tn = b >> 2; }
    const int tid = threadIdx.x;
    const unsigned lane = tid & 63, wid = tid >> 6;
    const unsigned wm = wid >> 1, wn = wid & 1;

    f32x4 acc[4][4];
#pragma unroll
    for (int i = 0; i < 4; ++i)
#pragma unroll
        for (int j = 0; j < 4; ++j) acc[i][j] = z4();

    const char* Abase = (const char*)A + (size_t)(tm * 128) * 2048;
    const char* Bbase = (const char*)B + (size_t)(tn * 128) * 2048;

    for (int ks = 0; ks < 16; ++ks) {
#pragma unroll
        for (int c = 0; c < 4; ++c) {
            unsigned g = wid * 256u + c * 64u + lane;
            unsigned r = g >> 3, sl = g & 7;
            gl16p(Abase + (size_t)r * 2048 + ks * 128 + sl * 16, (char*)Al + g * 16);
            gl16p(Bbase + (size_t)r * 2048 + ks * 128 + sl * 16, (char*)Bl + g * 16);
        }
        __syncthreads();
#pragma unroll
        for (int kk = 0; kk < 2; ++kk) {
            bf16x8 af[4], bg[4];
#pragma unroll
            for (int mt = 0; mt < 4; ++mt) {
                unsigned row = wm * 64 + mt * 16 + (lane & 15);
                af[mt] = *(const bf16x8*)((const char*)Al + row * 128 + kk * 64 + (lane >> 4) * 16);
            }
#pragma unroll
            for (int nt = 0; nt < 4; ++nt) {
                unsigned row = wn * 64 + nt * 16 + (lane & 15);
                bg[nt] = *(const bf16x8*)((const char*)Bl + row * 128 + kk * 64 + (lane >> 4) * 16);
            }
#pragma unroll
            for (int mt = 0; mt < 4; ++mt)
#pragma unroll
                for (int nt = 0; nt < 4; ++nt)
                    acc[mt][nt] = __builtin_amdgcn_mfma_f32_16x16x32_bf16(af[mt], bg[nt], acc[mt][nt], 0, 0, 0);
        }
        __syncthreads();
    }
#pragma unroll
    for (int mt = 0; mt < 4; ++mt)
#pragma unroll
        for (int nt = 0; nt < 4; ++nt)
#pragma unroll
            for (int rg = 0; rg < 4; ++rg) {
                int grow = tm * 128 + wm * 64 + mt * 16 + (lane >> 4) * 4 + rg;
                int gcol = tn * 128 + wn * 64 + nt * 16 + (lane & 15);
                float v = acc[mt][nt][rg] + (brow ? bias[grow] : bias[gcol]);
                C[(size_t)grow * ldc + gcol] = f2bf(v);
            }
}

// ---------------- colsum of v (row sums of vT) ----------------
__global__ __launch_bounds__(256) void colsum_kernel(const char* __restrict__ ws)
{
    const ushort_t* vT = (const ushort_t*)(ws + OFF_VT);
    float* cs = (float*)(ws + OFF_CS);
    const int d = blockIdx.x;
    const ushort4* row = (const ushort4*)(vT + (size_t)d * 8192);
    float s = 0.f;
    for (int i = threadIdx.x; i < 2048; i += 256) {
        ushort4 u = row[i];
        s += bf2f(u.x) + bf2f(u.y) + bf2f(u.z) + bf2f(u.w);
    }
    __shared__ float red[256];
    red[threadIdx.x] = s;
    __syncthreads();
    for (int st = 128; st > 0; st >>= 1) {
        if ((int)threadIdx.x < st) red[threadIdx.x] += red[threadIdx.x + st];
        __syncthreads();
    }
    if (threadIdx.x == 0) cs[d] = red[0];
}

// ---------------- pass1: P = exp(tanh(q k^T) / sqrt(512)) as bf16, chunked over j ----------------
// C tile 128x128, A = q [8192][512], B = k rows (j0 + tn*128 ..), K = 512 (8 ksteps of 64)
__global__ __launch_bounds__(256) void pass1_kernel(const char* __restrict__ ws, int JC, int j0)
{
    __shared__ ushort_t Al[128 * 64];
    __shared__ ushort_t Bl[128 * 64];
    const char* Abase = ws + OFF_Q + (size_t)(blockIdx.x * 128) * 1024;
    const char* Bbase = ws + OFF_K + (size_t)(j0 + blockIdx.y * 128) * 1024;
    ushort_t* P = (ushort_t*)(ws + OFF_P);
    const int tid = threadIdx.x;
    const unsigned lane = tid & 63, wid = tid >> 6;
    const unsigned wm = wid >> 1, wn = wid & 1;

    f32x4 acc[4][4];
#pragma unroll
    for (int i = 0; i < 4; ++i)
#pragma unroll
        for (int j = 0; j < 4; ++j) acc[i][j] = z4();

    for (int ks = 0; ks < 8; ++ks) {
#pragma unroll
        for (int c = 0; c < 4; ++c) {
            unsigned g = wid * 256u + c * 64u + lane;
            unsigned r = g >> 3, sl = (g & 7) ^ (r & 7);
            gl16p(Abase + (size_t)r * 1024 + ks * 128 + sl * 16, (char*)Al + g * 16);
            gl16p(Bbase + (size_t)r * 1024 + ks * 128 + sl * 16, (char*)Bl + g * 16);
        }
        __syncthreads();
#pragma unroll
        for (int kk = 0; kk < 2; ++kk) {
            bf16x8 af[4], bg[4];
#pragma unroll
            for (int mt = 0; mt < 4; ++mt) {
                unsigned row = wm * 64 + mt * 16 + (lane & 15);
                unsigned b = (kk * 4 + (lane >> 4)) ^ (row & 7);
                af[mt] = *(const bf16x8*)((const char*)Al + row * 128 + b * 16);
            }
#pragma unroll
            for (int nt = 0; nt < 4; ++nt) {
                unsigned row = wn * 64 + nt * 16 + (lane & 15);
                unsigned b = (kk * 4 + (lane >> 4)) ^ (row & 7);
                bg[nt] = *(const bf16x8*)((const char*)Bl + row * 128 + b * 16);
            }
#pragma unroll
            for (int mt = 0; mt < 4; ++mt)
#pragma unroll
                for (int nt = 0; nt < 4; ++nt)
                    acc[mt][nt] = __builtin_amdgcn_mfma_f32_16x16x32_bf16(af[mt], bg[nt], acc[mt][nt], 0, 0, 0);
        }
        __syncthreads();
    }
    const float csc = 0.044194173824159216f;  // 1/sqrt(512)
#pragma unroll
    for (int mt = 0; mt < 4; ++mt)
#pragma unroll
        for (int nt = 0; nt < 4; ++nt)
#pragma unroll
            for (int rg = 0; rg < 4; ++rg) {
                unsigned grow = blockIdx.x * 128 + wm * 64 + mt * 16 + (lane >> 4) * 4 + rg;
                unsigned gcol = blockIdx.y * 128 + wn * 64 + nt * 16 + (lane & 15);
                float s = acc[mt][nt][rg];
                float e = __expf(2.0f * s);
                float rr = __builtin_amdgcn_rcpf(1.0f + e);
                float t = fmaf(-2.0f, rr, 1.0f);               // tanh(s)
                float u = t * csc;
                float p = fmaf(u, fmaf(u, 0.5f, 1.0f), 1.0f);  // exp(u), |u|<=0.045
                P[(size_t)grow * JC + gcol] = f2bf(p);
            }
}

// ---------------- pass2: O += P @ vT-chunk, l += P @ ones; K split over blockIdx.z ----------------
// A = P [8192][JC], B = vT rows d (stride 8192), C tile 128x128 over [8192][512]
__global__ __launch_bounds__(256) void pass2_kernel(const char* __restrict__ ws, int JC, int j0, int first)
{
    __shared__ ushort_t Al[128 * 64];
    __shared__ ushort_t Bl[128 * 64];
    const char* Abase = ws + OFF_P + (size_t)(blockIdx.x * 128) * (JC * 2);
    const char* Bbase = ws + OFF_VT + (size_t)(blockIdx.y * 128) * 16384 + (size_t)j0 * 2;
    float* O = (float*)(ws + (blockIdx.z ? OFF_O2 : OFF_O));
    float* l = (float*)(ws + (blockIdx.z ? OFF_L2 : OFF_L));
    const int tid = threadIdx.x;
    const unsigned lane = tid & 63, wid = tid >> 6;
    const unsigned wm = wid >> 1, wn = wid & 1;
    const bool dol = (blockIdx.y == 0 && wn == 0);
    const int nkh = JC / 128;                 // (JC/64)/2 ksteps per z-half
    const int ks0 = blockIdx.z * nkh;

    bf16x8 vone;
#pragma unroll
    for (int i = 0; i < 8; ++i) vone[i] = (__bf16)1.0f;

    f32x4 acc[4][4];
#pragma unroll
    for (int i = 0; i < 4; ++i)
#pragma unroll
        for (int j = 0; j < 4; ++j) acc[i][j] = z4();
    f32x4 lacc[4];
#pragma unroll
    for (int i = 0; i < 4; ++i) lacc[i] = z4();

    for (int ks = ks0; ks < ks0 + nkh; ++ks) {
#pragma unroll
        for (int c = 0; c < 4; ++c) {
            unsigned g = wid * 256u + c * 64u + lane;
            unsigned r = g >> 3, sl = (g & 7) ^ (r & 7);
            gl16p(Abase + (size_t)r * (JC * 2) + ks * 128 + sl * 16, (char*)Al + g * 16);
            gl16p(Bbase + (size_t)r * 16384 + ks * 128 + sl * 16, (char*)Bl + g * 16);
        }
        __syncthreads();
#pragma unroll
        for (int kk = 0; kk < 2; ++kk) {
            bf16x8 af[4], bg[4];
#pragma unroll
            for (int mt = 0; mt < 4; ++mt) {
                unsigned row = wm * 64 + mt * 16 + (lane & 15);
                unsigned b = (kk * 4 + (lane >> 4)) ^ (row & 7);
                af[mt] = *(const bf16x8*)((const char*)Al + row * 128 + b * 16);
            }
#pragma unroll
            for (int nt = 0; nt < 4; ++nt) {
                unsigned row = wn * 64 + nt * 16 + (lane & 15);
                unsigned b = (kk * 4 + (lane >> 4)) ^ (row & 7);
                bg[nt] = *(const bf16x8*)((const char*)Bl + row * 128 + b * 16);
            }
            if (dol) {
#pragma unroll
                for (int mt = 0; mt < 4; ++mt)
                    lacc[mt] = __builtin_amdgcn_mfma_f32_16x16x32_bf16(af[mt], vone, lacc[mt], 0, 0, 0);
            }
#pragma unroll
            for (int mt = 0; mt < 4; ++mt)
#pragma unroll
                for (int nt = 0; nt < 4; ++nt)
                    acc[mt][nt] = __builtin_amdgcn_mfma_f32_16x16x32_bf16(af[mt], bg[nt], acc[mt][nt], 0, 0, 0);
        }
        __syncthreads();
    }
#pragma unroll
    for (int mt = 0; mt < 4; ++mt)
#pragma unroll
        for (int nt = 0; nt < 4; ++nt)
#pragma unroll
            for (int rg = 0; rg < 4; ++rg) {
                unsigned grow = blockIdx.x * 128 + wm * 64 + mt * 16 + (lane >> 4) * 4 + rg;
                unsigned gcol = blockIdx.y * 128 + wn * 64 + nt * 16 + (lane & 15);
                size_t oi = (size_t)grow * 512 + gcol;
                float v = acc[mt][nt][rg];
                O[oi] = first ? v : (O[oi] + v);
            }
    if (dol && (lane & 15) == 0) {
#pragma unroll
        for (int mt = 0; mt < 4; ++mt)
#pragma unroll
            for (int rg = 0; rg < 4; ++rg) {
                unsigned grow = blockIdx.x * 128 + wm * 64 + mt * 16 + (lane >> 4) * 4 + rg;
                float v = lacc[mt][rg];
                l[grow] = first ? v : (l[grow] + v);
            }
    }
}

// ---------------- final combine ----------------
__global__ __launch_bounds__(256) void out_kernel(const char* __restrict__ ws, float* __restrict__ out)
{
    const float* O  = (const float*)(ws + OFF_O);
    const float* O2 = (const float*)(ws + OFF_O2);
    const float* l  = (const float*)(ws + OFF_L);
    const float* l2 = (const float*)(ws + OFF_L2);
    const float* cs = (const float*)(ws + OFF_CS);
    unsigned idx = blockIdx.x * 256u + threadIdx.x;   // [0, 1048576)
    unsigned i = idx >> 7, dq = idx & 127;
    float li = l[i] + l2[i];
    float4 a = ((const float4*)O)[idx];
    float4 b = ((const float4*)O2)[idx];
    float4 c = ((const float4*)cs)[dq];
    float rinv = 1.0f / li;
    const float inv = 1.0f / 8191.0f;
    float4 r;
    r.x = (c.x - (a.x + b.x) * rinv) * inv;
    r.y = (c.y - (a.y + b.y) * rinv) * inv;
    r.z = (c.z - (a.z + b.z) * rinv) * inv;
    r.w = (c.w - (a.w + b.w) * rinv) * inv;
    ((float4*)out)[idx] = r;
}

extern "C" void kernel_launch(void* const* d_in, const int* in_sizes, int n_in,
                              void* d_out, int out_size, void* d_ws, size_t ws_size,
                              hipStream_t stream)
{
    const float* x1 = (const float*)d_in[0];
    const float* x2 = (const float*)d_in[1];
    const float* Wq = (const float*)d_in[2];
    const float* bq = (const float*)d_in[3];
    const float* Wk = (const float*)d_in[4];
    const float* bk = (const float*)d_in[5];
    const float* Wv = (const float*)d_in[6];
    const float* bv = (const float*)d_in[7];
    char* ws = (char*)d_ws;
    float* out = (float*)d_out;

    int JC;
    if      (ws_size >= (size_t)OFF_P + 134217728ull) JC = 8192;
    else if (ws_size >= (size_t)OFF_P +  67108864ull) JC = 4096;
    else if (ws_size >= (size_t)OFF_P +  33554432ull) JC = 2048;
    else if (ws_size >= (size_t)OFF_P +  16777216ull) JC = 1024;
    else                                              JC = 512;
    int NC = 8192 / JC;

    cvt_kernel<<<4096, 256, 0, stream>>>(x1, x2, Wq, Wk, Wv, ws);
    proj_kernel<<<dim3(256, 3), 256, 0, stream>>>(ws, bq, bk, bv);
    colsum_kernel<<<512, 256, 0, stream>>>(ws);
    for (int c = 0; c < NC; ++c) {
        pass1_kernel<<<dim3(64, JC / 128), 256, 0, stream>>>(ws, JC, c * JC);
        pass2_kernel<<<dim3(64, 4, 2), 256, 0, stream>>>(ws, JC, c * JC, c == 0);
    }
    out_kernel<<<4096, 256, 0, stream>>>(ws, out);
}

// Round 3
// 250.742 us; speedup vs baseline: 2.1476x; 1.1062x over previous
//
#include <hip/hip_runtime.h>

typedef unsigned short ushort_t;

typedef __bf16 bf16x8 __attribute__((ext_vector_type(8)));
typedef float f32x4 __attribute__((ext_vector_type(4)));

// workspace byte offsets
#define OFF_X1B 0u            // reused as l1p [8192][128] f32 after proj
#define OFF_X2B 16777216u
#define OFF_WQB 33554432u
#define OFF_WKB 34603008u
#define OFF_WVB 35651584u
#define OFF_Q   36700160u
#define OFF_K   45088768u
#define OFF_VT  53477376u
#define OFF_CS  61865984u
#define OFF_L   61868032u
#define OFF_O   61933568u     // 4 x [8192][512] bf16 partials (z-split)
#define OFF_P   95488000u     // [8192][8192] bf16

__device__ __forceinline__ float bf2f(ushort_t u) {
    unsigned x = ((unsigned)u) << 16;
    return __uint_as_float(x);
}
__device__ __forceinline__ ushort_t f2bf(float f) {
    unsigned u = __float_as_uint(f);
    return (ushort_t)((u + 0x7FFFu + ((u >> 16) & 1u)) >> 16);
}

typedef __attribute__((address_space(1))) void gv_t;
typedef __attribute__((address_space(3))) void lv_t;
__device__ __forceinline__ void gl16p(const void* g, void* l) {
    __builtin_amdgcn_global_load_lds((gv_t*)g, (lv_t*)l, 16, 0, 0);
}

__device__ __forceinline__ f32x4 z4() {
    f32x4 v;
#pragma unroll
    for (int i = 0; i < 4; ++i) v[i] = 0.f;
    return v;
}

// ---------------- convert f32 -> bf16 ----------------
__global__ __launch_bounds__(256) void cvt_kernel(
    const float* __restrict__ x1, const float* __restrict__ x2,
    const float* __restrict__ Wq, const float* __restrict__ Wk,
    const float* __restrict__ Wv, char* __restrict__ ws)
{
    ushort_t* x1b = (ushort_t*)(ws + OFF_X1B);
    ushort_t* x2b = (ushort_t*)(ws + OFF_X2B);
    ushort_t* wqb = (ushort_t*)(ws + OFF_WQB);
    ushort_t* wkb = (ushort_t*)(ws + OFF_WKB);
    ushort_t* wvb = (ushort_t*)(ws + OFF_WVB);
    const unsigned TOT4 = 4587520u;
    for (unsigned idx = blockIdx.x * 256u + threadIdx.x; idx < TOT4; idx += gridDim.x * 256u) {
        unsigned i = idx;
        const float* s; ushort_t* d;
        if (i < 2097152u)      { s = x1; d = x1b; }
        else if (i < 4194304u) { i -= 2097152u; s = x2; d = x2b; }
        else if (i < 4325376u) { i -= 4194304u; s = Wq; d = wqb; }
        else if (i < 4456448u) { i -= 4325376u; s = Wk; d = wkb; }
        else                   { i -= 4456448u; s = Wv; d = wvb; }
        float4 v = *(const float4*)(s + (size_t)i * 4);
        ushort4 o;
        o.x = f2bf(v.x); o.y = f2bf(v.y); o.z = f2bf(v.z); o.w = f2bf(v.w);
        *(ushort4*)(d + (size_t)i * 4) = o;
    }
}

// ---------------- projection GEMMs (m97-style, known good) ----------------
__global__ __launch_bounds__(256) void proj_kernel(
    const char* __restrict__ ws,
    const float* __restrict__ bq, const float* __restrict__ bk, const float* __restrict__ bv)
{
    __shared__ ushort_t Al[128 * 64];
    __shared__ ushort_t Bl[128 * 64];
    const int z = blockIdx.y;
    const ushort_t* A; const ushort_t* B; const float* bias; ushort_t* C;
    int ldc; bool brow;
    if (z == 0)      { A = (const ushort_t*)(ws + OFF_X1B); B = (const ushort_t*)(ws + OFF_WQB); bias = bq; C = (ushort_t*)(ws + OFF_Q);  ldc = 512;  brow = false; }
    else if (z == 1) { A = (const ushort_t*)(ws + OFF_X2B); B = (const ushort_t*)(ws + OFF_WKB); bias = bk; C = (ushort_t*)(ws + OFF_K);  ldc = 512;  brow = false; }
    else             { A = (const ushort_t*)(ws + OFF_WVB); B = (const ushort_t*)(ws + OFF_X2B); bias = bv; C = (ushort_t*)(ws + OFF_VT); ldc = 8192; brow = true;  }
    const int b = blockIdx.x;
    int tm, tn;
    if (z < 2) { tm = b >> 2; tn = b & 3; } else { tm = b & 3; tn = b >> 2; }
    const int tid = threadIdx.x;
    const unsigned lane = tid & 63, wid = tid >> 6;
    const unsigned wm = wid >> 1, wn = wid & 1;

    f32x4 acc[4][4];
#pragma unroll
    for (int i = 0; i < 4; ++i)
#pragma unroll
        for (int j = 0; j < 4; ++j) acc[i][j] = z4();

    const char* Abase = (const char*)A + (size_t)(tm * 128) * 2048;
    const char* Bbase = (const char*)B + (size_t)(tn * 128) * 2048;

    for (int ks = 0; ks < 16; ++ks) {
#pragma unroll
        for (int c = 0; c < 4; ++c) {
            unsigned g = wid * 256u + c * 64u + lane;
            unsigned r = g >> 3, sl = g & 7;
            gl16p(Abase + (size_t)r * 2048 + ks * 128 + sl * 16, (char*)Al + g * 16);
            gl16p(Bbase + (size_t)r * 2048 + ks * 128 + sl * 16, (char*)Bl + g * 16);
        }
        __syncthreads();
#pragma unroll
        for (int kk = 0; kk < 2; ++kk) {
            bf16x8 af[4], bg[4];
#pragma unroll
            for (int mt = 0; mt < 4; ++mt) {
                unsigned row = wm * 64 + mt * 16 + (lane & 15);
                af[mt] = *(const bf16x8*)((const char*)Al + row * 128 + kk * 64 + (lane >> 4) * 16);
            }
#pragma unroll
            for (int nt = 0; nt < 4; ++nt) {
                unsigned row = wn * 64 + nt * 16 + (lane & 15);
                bg[nt] = *(const bf16x8*)((const char*)Bl + row * 128 + kk * 64 + (lane >> 4) * 16);
            }
#pragma unroll
            for (int mt = 0; mt < 4; ++mt)
#pragma unroll
                for (int nt = 0; nt < 4; ++nt)
                    acc[mt][nt] = __builtin_amdgcn_mfma_f32_16x16x32_bf16(af[mt], bg[nt], acc[mt][nt], 0, 0, 0);
        }
        __syncthreads();
    }
#pragma unroll
    for (int mt = 0; mt < 4; ++mt)
#pragma unroll
        for (int nt = 0; nt < 4; ++nt)
#pragma unroll
            for (int rg = 0; rg < 4; ++rg) {
                int grow = tm * 128 + wm * 64 + mt * 16 + (lane >> 4) * 4 + rg;
                int gcol = tn * 128 + wn * 64 + nt * 16 + (lane & 15);
                float v = acc[mt][nt][rg] + (brow ? bias[grow] : bias[gcol]);
                C[(size_t)grow * ldc + gcol] = f2bf(v);
            }
}

// ---------------- colsum of v (row sums of vT) ----------------
__global__ __launch_bounds__(256) void colsum_kernel(const char* __restrict__ ws)
{
    const ushort_t* vT = (const ushort_t*)(ws + OFF_VT);
    float* cs = (float*)(ws + OFF_CS);
    const int d = blockIdx.x;
    const ushort4* row = (const ushort4*)(vT + (size_t)d * 8192);
    float s = 0.f;
    for (int i = threadIdx.x; i < 2048; i += 256) {
        ushort4 u = row[i];
        s += bf2f(u.x) + bf2f(u.y) + bf2f(u.z) + bf2f(u.w);
    }
    __shared__ float red[256];
    red[threadIdx.x] = s;
    __syncthreads();
    for (int st = 128; st > 0; st >>= 1) {
        if ((int)threadIdx.x < st) red[threadIdx.x] += red[threadIdx.x + st];
        __syncthreads();
    }
    if (threadIdx.x == 0) cs[d] = red[0];
}

// ---------------- 256x256 8-phase GEMM core (T2+T3+T4+T5) ----------------
// LDS: dbuf d in {0,1} at d*65536: A halves [0,16384), B halves at +32768.
// Half-tile = 128 rows x 64 cols bf16 (16KB), swizzle byte ^= ((r&7)<<4).
__device__ __forceinline__ void stage_half(const char* gbase, size_t ld, unsigned kbyte,
                                           char* lds_half, unsigned tid)
{
#pragma unroll
    for (int u = 0; u < 2; ++u) {
        unsigned slot = tid + u * 512u;            // 0..1023
        unsigned r = slot >> 3;                    // 0..127
        unsigned cb = (slot & 7u) << 4;            // 0..112
        unsigned cbs = cb ^ ((r & 7u) << 4);       // pre-swizzled source col
        gl16p(gbase + (size_t)r * ld + kbyte + cbs, lds_half + slot * 16u);
    }
}

__device__ __forceinline__ void gemm_loop_8p(char* smem, const char* Abase, size_t lda,
                                             const char* Bbase, size_t ldb, int nks,
                                             unsigned tid, f32x4 (&acc)[8][4])
{
    const unsigned lane = tid & 63, wid = tid >> 6;
    const unsigned wm = wid >> 2, wn = wid & 3;

    // prologue: K-step 0 into buf0
    stage_half(Abase,             lda, 0, smem +     0, tid);
    stage_half(Abase + 128 * lda, lda, 0, smem + 16384, tid);
    stage_half(Bbase,             ldb, 0, smem + 32768, tid);
    stage_half(Bbase + 128 * ldb, ldb, 0, smem + 49152, tid);

    for (int t = 0; t < nks; ++t) {
        const unsigned cur = (unsigned)(t & 1) * 65536u;
        const unsigned nxt = 65536u - cur;
        const char* ldsA = smem + cur + wm * 16384u;
        const char* ldsB = smem + cur + 32768u + (wn >> 1) * 16384u;
        const int tp = (t + 1 < nks) ? (t + 1) : t;   // clamp: keep vmcnt counts uniform
        const unsigned kb = (unsigned)tp * 128u;

        bf16x8 af[2][4][2];   // [mh][m2][ks]
        bf16x8 bg[2][2][2];   // [nh][n2][ks]

        // ---- phase 0: quadrant (mh0, nh0) ----
        stage_half(Abase,             lda, kb, smem + nxt,          tid);
        stage_half(Abase + 128 * lda, lda, kb, smem + nxt + 16384u, tid);
        asm volatile("s_waitcnt vmcnt(4)" ::: "memory");   // this K-step's 4 halves landed
        __builtin_amdgcn_s_barrier();
#pragma unroll
        for (int m2 = 0; m2 < 4; ++m2) {
            unsigned rA = m2 * 16u + (lane & 15);
#pragma unroll
            for (int ks = 0; ks < 2; ++ks)
                af[0][m2][ks] = *(const bf16x8*)(ldsA + rA * 128u + (((ks * 4u + (lane >> 4)) * 16u) ^ ((rA & 7u) << 4)));
        }
#pragma unroll
        for (int n2 = 0; n2 < 2; ++n2) {
            unsigned rB = (wn & 1) * 64u + n2 * 16u + (lane & 15);
#pragma unroll
            for (int ks = 0; ks < 2; ++ks)
                bg[0][n2][ks] = *(const bf16x8*)(ldsB + rB * 128u + (((ks * 4u + (lane >> 4)) * 16u) ^ ((rB & 7u) << 4)));
        }
        __builtin_amdgcn_s_setprio(1);
#pragma unroll
        for (int m2 = 0; m2 < 4; ++m2)
#pragma unroll
            for (int n2 = 0; n2 < 2; ++n2)
#pragma unroll
                for (int ks = 0; ks < 2; ++ks)
                    acc[m2][n2] = __builtin_amdgcn_mfma_f32_16x16x32_bf16(af[0][m2][ks], bg[0][n2][ks], acc[m2][n2], 0, 0, 0);
        __builtin_amdgcn_s_setprio(0);
        __builtin_amdgcn_s_barrier();

        // ---- phase 1: quadrant (mh0, nh1) ----
#pragma unroll
        for (int n2 = 0; n2 < 2; ++n2) {
            unsigned rB = (wn & 1) * 64u + (2 + n2) * 16u + (lane & 15);
#pragma unroll
            for (int ks = 0; ks < 2; ++ks)
                bg[1][n2][ks] = *(const bf16x8*)(ldsB + rB * 128u + (((ks * 4u + (lane >> 4)) * 16u) ^ ((rB & 7u) << 4)));
        }
        stage_half(Bbase,             ldb, kb, smem + nxt + 32768u, tid);
        stage_half(Bbase + 128 * ldb, ldb, kb, smem + nxt + 49152u, tid);
        __builtin_amdgcn_s_barrier();
        __builtin_amdgcn_s_setprio(1);
#pragma unroll
        for (int m2 = 0; m2 < 4; ++m2)
#pragma unroll
            for (int n2 = 0; n2 < 2; ++n2)
#pragma unroll
                for (int ks = 0; ks < 2; ++ks)
                    acc[m2][2 + n2] = __builtin_amdgcn_mfma_f32_16x16x32_bf16(af[0][m2][ks], bg[1][n2][ks], acc[m2][2 + n2], 0, 0, 0);
        __builtin_amdgcn_s_setprio(0);
        __builtin_amdgcn_s_barrier();

        // ---- phase 2: quadrant (mh1, nh0) ----
#pragma unroll
        for (int m2 = 0; m2 < 4; ++m2) {
            unsigned rA = (4 + m2) * 16u + (lane & 15);
#pragma unroll
            for (int ks = 0; ks < 2; ++ks)
                af[1][m2][ks] = *(const bf16x8*)(ldsA + rA * 128u + (((ks * 4u + (lane >> 4)) * 16u) ^ ((rA & 7u) << 4)));
        }
        __builtin_amdgcn_s_barrier();
        __builtin_amdgcn_s_setprio(1);
#pragma unroll
        for (int m2 = 0; m2 < 4; ++m2)
#pragma unroll
            for (int n2 = 0; n2 < 2; ++n2)
#pragma unroll
                for (int ks = 0; ks < 2; ++ks)
                    acc[4 + m2][n2] = __builtin_amdgcn_mfma_f32_16x16x32_bf16(af[1][m2][ks], bg[0][n2][ks], acc[4 + m2][n2], 0, 0, 0);
        __builtin_amdgcn_s_setprio(0);
        __builtin_amdgcn_s_barrier();

        // ---- phase 3: quadrant (mh1, nh1) ----
        __builtin_amdgcn_s_setprio(1);
#pragma unroll
        for (int m2 = 0; m2 < 4; ++m2)
#pragma unroll
            for (int n2 = 0; n2 < 2; ++n2)
#pragma unroll
                for (int ks = 0; ks < 2; ++ks)
                    acc[4 + m2][2 + n2] = __builtin_amdgcn_mfma_f32_16x16x32_bf16(af[1][m2][ks], bg[1][n2][ks], acc[4 + m2][2 + n2], 0, 0, 0);
        __builtin_amdgcn_s_setprio(0);
        __builtin_amdgcn_s_barrier();
    }
    asm volatile("s_waitcnt vmcnt(0)" ::: "memory");   // drain clamped tail prefetch
}

// ---------------- pass1: P = exp(tanh(q k^T)/sqrt(512)) bf16 + l partials ----------------
__global__ __launch_bounds__(512, 2) void pass1_kernel(char* __restrict__ ws)
{
    extern __shared__ char smem[];
    const unsigned bid = blockIdx.x;
    const unsigned wg = (bid & 7u) * 128u + (bid >> 3);   // XCD-aware swizzle (1024 % 8 == 0)
    const unsigned tm = wg >> 5, tn = wg & 31u;
    const unsigned tid = threadIdx.x;
    const unsigned lane = tid & 63, wid = tid >> 6;
    const unsigned wm = wid >> 2, wn = wid & 3;

    f32x4 acc[8][4];
#pragma unroll
    for (int i = 0; i < 8; ++i)
#pragma unroll
        for (int j = 0; j < 4; ++j) acc[i][j] = z4();

    const char* Abase = ws + OFF_Q + (size_t)(tm * 256) * 1024;
    const char* Bbase = ws + OFF_K + (size_t)(tn * 256) * 1024;
    gemm_loop_8p(smem, Abase, 1024, Bbase, 1024, 8, tid, acc);

    ushort_t* P = (ushort_t*)(ws + OFF_P);
    float* l1p = (float*)(ws + OFF_X1B);
    const float csc = 0.044194173824159216f;  // 1/sqrt(512)
    float rs[8][4];
#pragma unroll
    for (int mt = 0; mt < 8; ++mt)
#pragma unroll
        for (int rg = 0; rg < 4; ++rg) rs[mt][rg] = 0.f;

#pragma unroll
    for (int mt = 0; mt < 8; ++mt)
#pragma unroll
        for (int nt = 0; nt < 4; ++nt)
#pragma unroll
            for (int rg = 0; rg < 4; ++rg) {
                unsigned grow = tm * 256 + wm * 128 + mt * 16 + (lane >> 4) * 4 + rg;
                unsigned gcol = tn * 256 + wn * 64 + nt * 16 + (lane & 15);
                float s = acc[mt][nt][rg];
                float e = __expf(2.0f * s);
                float rr = __builtin_amdgcn_rcpf(1.0f + e);
                float tt = fmaf(-2.0f, rr, 1.0f);               // tanh(s)
                float u = tt * csc;
                float p = fmaf(u, fmaf(u, 0.5f, 1.0f), 1.0f);   // exp(u), |u|<=0.045
                P[(size_t)grow * 8192 + gcol] = f2bf(p);
                rs[mt][rg] += p;
            }
    // reduce across the 16 lanes holding this row's 4-col groups -> 64-col sums
#pragma unroll
    for (int mt = 0; mt < 8; ++mt)
#pragma unroll
        for (int rg = 0; rg < 4; ++rg) {
            float v = rs[mt][rg];
            v += __shfl_xor(v, 1);
            v += __shfl_xor(v, 2);
            v += __shfl_xor(v, 4);
            v += __shfl_xor(v, 8);
            rs[mt][rg] = v;
        }
    if ((lane & 15) == 0) {
        unsigned colblk = tn * 4 + wn;   // 0..127
#pragma unroll
        for (int mt = 0; mt < 8; ++mt)
#pragma unroll
            for (int rg = 0; rg < 4; ++rg) {
                unsigned grow = tm * 256 + wm * 128 + mt * 16 + (lane >> 4) * 4 + rg;
                l1p[(size_t)grow * 128 + colblk] = rs[mt][rg];
            }
    }
}

// ---------------- lsum: l[i] = sum over 128 col-blocks ----------------
__global__ __launch_bounds__(256) void lsum_kernel(char* __restrict__ ws)
{
    const float* l1p = (const float*)(ws + OFF_X1B);
    float* l = (float*)(ws + OFF_L);
    unsigned i = blockIdx.x * 256u + threadIdx.x;   // 0..8191
    const float4* p = (const float4*)(l1p + (size_t)i * 128);
    float s = 0.f;
#pragma unroll 4
    for (int c = 0; c < 32; ++c) {
        float4 v = p[c];
        s += v.x + v.y + v.z + v.w;
    }
    l[i] = s;
}

// ---------------- pass2: O_z = P[:, z-chunk] @ vT[:, z-chunk]^T (bf16 partials) ----------------
__global__ __launch_bounds__(512, 2) void pass2_kernel(char* __restrict__ ws)
{
    extern __shared__ char smem[];
    const unsigned bx = blockIdx.x, by = blockIdx.y, z = blockIdx.z;
    const unsigned tid = threadIdx.x;
    const unsigned lane = tid & 63, wid = tid >> 6;
    const unsigned wm = wid >> 2, wn = wid & 3;

    f32x4 acc[8][4];
#pragma unroll
    for (int i = 0; i < 8; ++i)
#pragma unroll
        for (int j = 0; j < 4; ++j) acc[i][j] = z4();

    const char* Abase = ws + OFF_P  + (size_t)(bx * 256) * 16384 + (size_t)z * 4096;
    const char* Bbase = ws + OFF_VT + (size_t)(by * 256) * 16384 + (size_t)z * 4096;
    gemm_loop_8p(smem, Abase, 16384, Bbase, 16384, 32, tid, acc);

    ushort_t* Opart = (ushort_t*)(ws + OFF_O + (size_t)z * 8388608);
#pragma unroll
    for (int mt = 0; mt < 8; ++mt)
#pragma unroll
        for (int nt = 0; nt < 4; ++nt)
#pragma unroll
            for (int rg = 0; rg < 4; ++rg) {
                unsigned grow = bx * 256 + wm * 128 + mt * 16 + (lane >> 4) * 4 + rg;
                unsigned gcol = by * 256 + wn * 64 + nt * 16 + (lane & 15);
                Opart[(size_t)grow * 512 + gcol] = f2bf(acc[mt][nt][rg]);
            }
}

// ---------------- final combine ----------------
__global__ __launch_bounds__(256) void out_kernel(const char* __restrict__ ws, float* __restrict__ out)
{
    const ushort_t* O0 = (const ushort_t*)(ws + OFF_O);
    const float* l  = (const float*)(ws + OFF_L);
    const float* cs = (const float*)(ws + OFF_CS);
    unsigned idx = blockIdx.x * 256u + threadIdx.x;   // [0, 1048576)
    unsigned i = idx >> 7, d4 = (idx & 127) * 4;
    float a0 = 0.f, a1 = 0.f, a2 = 0.f, a3 = 0.f;
#pragma unroll
    for (int z = 0; z < 4; ++z) {
        ushort4 u = *(const ushort4*)(O0 + (size_t)z * 4194304 + (size_t)i * 512 + d4);
        a0 += bf2f(u.x); a1 += bf2f(u.y); a2 += bf2f(u.z); a3 += bf2f(u.w);
    }
    float4 c = *(const float4*)(cs + d4);
    float rinv = 1.0f / l[i];
    const float inv = 1.0f / 8191.0f;
    float4 r;
    r.x = (c.x - a0 * rinv) * inv;
    r.y = (c.y - a1 * rinv) * inv;
    r.z = (c.z - a2 * rinv) * inv;
    r.w = (c.w - a3 * rinv) * inv;
    ((float4*)out)[idx] = r;
}

extern "C" void kernel_launch(void* const* d_in, const int* in_sizes, int n_in,
                              void* d_out, int out_size, void* d_ws, size_t ws_size,
                              hipStream_t stream)
{
    const float* x1 = (const float*)d_in[0];
    const float* x2 = (const float*)d_in[1];
    const float* Wq = (const float*)d_in[2];
    const float* bq = (const float*)d_in[3];
    const float* Wk = (const float*)d_in[4];
    const float* bk = (const float*)d_in[5];
    const float* Wv = (const float*)d_in[6];
    const float* bv = (const float*)d_in[7];
    char* ws = (char*)d_ws;
    float* out = (float*)d_out;

    (void)hipFuncSetAttribute((const void*)pass1_kernel,
                              hipFuncAttributeMaxDynamicSharedMemorySize, 131072);
    (void)hipFuncSetAttribute((const void*)pass2_kernel,
                              hipFuncAttributeMaxDynamicSharedMemorySize, 131072);

    cvt_kernel<<<4096, 256, 0, stream>>>(x1, x2, Wq, Wk, Wv, ws);
    proj_kernel<<<dim3(256, 3), 256, 0, stream>>>(ws, bq, bk, bv);
    colsum_kernel<<<512, 256, 0, stream>>>(ws);
    pass1_kernel<<<1024, 512, 131072, stream>>>(ws);
    lsum_kernel<<<32, 256, 0, stream>>>(ws);
    pass2_kernel<<<dim3(32, 2, 4), 512, 131072, stream>>>(ws);
    out_kernel<<<4096, 256, 0, stream>>>(ws, out);
}